// Round 2
// baseline (320.677 us; speedup 1.0000x reference)
//
#include <hip/hip_runtime.h>
#include <hip/hip_bf16.h>

#define BB 32
#define CC 256
#define GC 64
#define LL 64      // H == W == 64
#define HEADS 8
#define HD 32

// ---------------------------------------------------------------------------
// K1: per (b,c) plane (64x64): row means (over w), col means (over h),
//     8x8 patch-pool means.  One block per plane, 256 threads.
// ---------------------------------------------------------------------------
__global__ __launch_bounds__(256) void k_reduce(const float* __restrict__ x,
                                                float* __restrict__ xh,
                                                float* __restrict__ xw,
                                                float* __restrict__ y) {
    __shared__ float sm[64 * 65];   // padded stride 65 -> conflict-free
    const int bc  = blockIdx.x;     // b*C + c
    const int tid = threadIdx.x;
    const float* xp = x + (size_t)bc * 4096;

    for (int i = tid; i < 1024; i += 256) {
        float4 v = reinterpret_cast<const float4*>(xp)[i];
        int h = (i * 4) >> 6, w = (i * 4) & 63;
        float* row = &sm[h * 65 + w];
        row[0] = v.x; row[1] = v.y; row[2] = v.z; row[3] = v.w;
    }
    __syncthreads();

    const int q = tid & 3, r = tid >> 2;   // r in 0..63

    // row sums (mean over w) -> xh[b,c,h]
    float s = 0.f;
#pragma unroll
    for (int j = 0; j < 16; ++j) s += sm[r * 65 + q * 16 + j];
    s += __shfl_down(s, 2, 4);
    s += __shfl_down(s, 1, 4);
    if (q == 0) xh[(size_t)bc * 64 + r] = s * (1.0f / 64.0f);

    // col sums (mean over h) -> xw[b,c,w]
    s = 0.f;
#pragma unroll
    for (int j = 0; j < 16; ++j) s += sm[(q * 16 + j) * 65 + r];
    s += __shfl_down(s, 2, 4);
    s += __shfl_down(s, 1, 4);
    if (q == 0) xw[(size_t)bc * 64 + r] = s * (1.0f / 64.0f);

    // 8x8 patch means -> y[b,c,ph*8+pw]
    if (tid < 64) {
        int ph = tid >> 3, pw = tid & 7;
        float ps = 0.f;
        for (int rr = 0; rr < 8; ++rr)
#pragma unroll
            for (int cci = 0; cci < 8; ++cci)
                ps += sm[(ph * 8 + rr) * 65 + pw * 8 + cci];
        y[(size_t)bc * 64 + tid] = ps * (1.0f / 64.0f);
    }
}

// ---------------------------------------------------------------------------
// K2: strip attention.  One block per (b, dir, group): depthwise conv1d
//     (k = 3/5/7/9 per group) + GroupNorm(group of 64ch x 64len) + sigmoid.
// ---------------------------------------------------------------------------
__global__ __launch_bounds__(256) void k_strip(
        const float* __restrict__ xh, const float* __restrict__ xw,
        const float* __restrict__ dw1, const float* __restrict__ db1,
        const float* __restrict__ dw2, const float* __restrict__ db2,
        const float* __restrict__ dw3, const float* __restrict__ db3,
        const float* __restrict__ dw4, const float* __restrict__ db4,
        const float* __restrict__ gnh_w, const float* __restrict__ gnh_b,
        const float* __restrict__ gnw_w, const float* __restrict__ gnw_b,
        float* __restrict__ h_att, float* __restrict__ w_att) {
    __shared__ float sm[64 * 65];
    __shared__ float red[8];
    const int bx  = blockIdx.x;          // b*8 + dir*4 + g
    const int b   = bx >> 3;
    const int dir = (bx >> 2) & 1;
    const int g   = bx & 3;
    const int tid = threadIdx.x;

    const float* src = (dir ? xw : xh) + ((size_t)b * CC + g * GC) * 64;
    float*       dst = (dir ? w_att : h_att) + ((size_t)b * CC + g * GC) * 64;
    const float* gw  = (dir ? gnw_w : gnh_w) + g * GC;
    const float* gb  = (dir ? gnw_b : gnh_b) + g * GC;

    const float* dwp; const float* dbp; int k;
    if      (g == 0) { dwp = dw1; dbp = db1; k = 3; }
    else if (g == 1) { dwp = dw2; dbp = db2; k = 5; }
    else if (g == 2) { dwp = dw3; dbp = db3; k = 7; }
    else             { dwp = dw4; dbp = db4; k = 9; }

    for (int i = tid; i < 1024; i += 256) {
        float4 v = reinterpret_cast<const float4*>(src)[i];
        int ch = (i * 4) >> 6, l = (i * 4) & 63;
        float* row = &sm[ch * 65 + l];
        row[0] = v.x; row[1] = v.y; row[2] = v.z; row[3] = v.w;
    }
    __syncthreads();

    const int ch = tid >> 2, q = tid & 3;
    const int khalf = k >> 1;
    float wreg[9];
    for (int j = 0; j < 9; ++j) wreg[j] = (j < k) ? dwp[ch * k + j] : 0.0f;
    const float bias = dbp[ch];

    float o[16];
    float lsum = 0.f, lsq = 0.f;
    for (int i = 0; i < 16; ++i) {
        int l = q * 16 + i;
        float acc = bias;
        for (int j = 0; j < k; ++j) {
            int p = l + j - khalf;
            if (p >= 0 && p < 64) acc += wreg[j] * sm[ch * 65 + p];
        }
        o[i] = acc;
        lsum += acc; lsq += acc * acc;
    }
    // block reduce (sum, sumsq) over 4096 conv outputs
    for (int off = 32; off; off >>= 1) {
        lsum += __shfl_down(lsum, off, 64);
        lsq  += __shfl_down(lsq,  off, 64);
    }
    const int wid = tid >> 6, lane = tid & 63;
    if (lane == 0) { red[wid] = lsum; red[4 + wid] = lsq; }
    __syncthreads();
    const float tsum = red[0] + red[1] + red[2] + red[3];
    const float tsq  = red[4] + red[5] + red[6] + red[7];
    const float m    = tsum * (1.0f / 4096.0f);
    const float var  = tsq * (1.0f / 4096.0f) - m * m;
    const float rstd = rsqrtf(var + 1e-5f);
    const float gamma = gw[ch], beta = gb[ch];

    float outv[16];
#pragma unroll
    for (int i = 0; i < 16; ++i) {
        float v = (o[i] - m) * rstd * gamma + beta;
        outv[i] = 1.0f / (1.0f + __expf(-v));
    }
    float* dp = dst + ch * 64 + q * 16;
#pragma unroll
    for (int i = 0; i < 16; i += 4) {
        reinterpret_cast<float4*>(dp + i)[0] =
            make_float4(outv[i], outv[i + 1], outv[i + 2], outv[i + 3]);
    }
}

// ---------------------------------------------------------------------------
// K3: pooled channel self-attention.  One block per batch.
//     GN(groups=1) over (256,64), q/k/v per-channel scales, per-head 32x32
//     softmax, then c_att[ch] = sigmoid(sum_e att[d,e] * mean_n v[e,n]).
// ---------------------------------------------------------------------------
__global__ __launch_bounds__(256) void k_pool_att(
        const float* __restrict__ y,
        const float* __restrict__ norm_w, const float* __restrict__ norm_b,
        const float* __restrict__ wq, const float* __restrict__ wk,
        const float* __restrict__ wv, float* __restrict__ c_att) {
    __shared__ float yn[CC * 65];   // padded
    __shared__ float vbar[CC];
    __shared__ float kwv[CC];
    __shared__ float red[8];
    const int b = blockIdx.x, tid = threadIdx.x;
    const float* yp = y + (size_t)b * CC * 64;

    for (int i = tid; i < 4096; i += 256) {
        float4 v = reinterpret_cast<const float4*>(yp)[i];
        int ch = (i * 4) >> 6, n0 = (i * 4) & 63;
        float* row = &yn[ch * 65 + n0];
        row[0] = v.x; row[1] = v.y; row[2] = v.z; row[3] = v.w;
    }
    __syncthreads();

    const int ch = tid;              // one channel per thread
    float lsum = 0.f, lsq = 0.f;
    for (int n = 0; n < 64; ++n) {
        float v = yn[ch * 65 + n];
        lsum += v; lsq += v * v;
    }
    for (int off = 32; off; off >>= 1) {
        lsum += __shfl_down(lsum, off, 64);
        lsq  += __shfl_down(lsq,  off, 64);
    }
    const int wid = tid >> 6, lane = tid & 63;
    if (lane == 0) { red[wid] = lsum; red[4 + wid] = lsq; }
    __syncthreads();
    const float tsum = red[0] + red[1] + red[2] + red[3];
    const float tsq  = red[4] + red[5] + red[6] + red[7];
    const float m    = tsum * (1.0f / 16384.0f);
    const float var  = tsq * (1.0f / 16384.0f) - m * m;
    const float rstd = rsqrtf(var + 1e-5f);

    // normalize in place + per-channel v-row mean
    const float gamma = norm_w[ch], beta = norm_b[ch];
    float rs = 0.f;
    for (int n = 0; n < 64; ++n) {
        float v = (yn[ch * 65 + n] - m) * rstd * gamma + beta;
        yn[ch * 65 + n] = v;
        rs += v;
    }
    vbar[ch] = rs * (1.0f / 64.0f) * wv[ch];
    kwv[ch]  = wk[ch];
    __syncthreads();

    const int head = ch >> 5;
    const float qs = wq[ch] * 0.17677669529663687f;   // * hd^-0.5
    const float* myrow = &yn[ch * 65];
    float s[HD];
    for (int e = 0; e < HD; ++e) {
        const float* erow = &yn[(head * HD + e) * 65];
        float acc = 0.f;
#pragma unroll
        for (int n = 0; n < 64; ++n) acc += myrow[n] * erow[n];
        s[e] = acc * qs * kwv[head * HD + e];
    }
    float mx = s[0];
#pragma unroll
    for (int e = 1; e < HD; ++e) mx = fmaxf(mx, s[e]);
    float den = 0.f;
#pragma unroll
    for (int e = 0; e < HD; ++e) { s[e] = __expf(s[e] - mx); den += s[e]; }
    float o = 0.f;
#pragma unroll
    for (int e = 0; e < HD; ++e) o += s[e] * vbar[head * HD + e];
    o /= den;
    c_att[(size_t)b * CC + ch] = 1.0f / (1.0f + __expf(-o));
}

// ---------------------------------------------------------------------------
// K4: out = x * (h_att[b,c,h] * w_att[b,c,w] + c_att[b,c])
// ---------------------------------------------------------------------------
__global__ __launch_bounds__(256) void k_final(
        const float* __restrict__ x, const float* __restrict__ h_att,
        const float* __restrict__ w_att, const float* __restrict__ c_att,
        float* __restrict__ out) {
    const size_t total4 = (size_t)BB * CC * LL * LL / 4;   // 8,388,608
    const size_t stride = (size_t)gridDim.x * blockDim.x;
    for (size_t i = (size_t)blockIdx.x * blockDim.x + threadIdx.x;
         i < total4; i += stride) {
        size_t lin = i * 4;
        int w = (int)(lin & 63);
        int h = (int)((lin >> 6) & 63);
        size_t bc = lin >> 12;          // b*C + c
        float ha = h_att[bc * 64 + h];
        float ca = c_att[bc];
        float4 wa = reinterpret_cast<const float4*>(w_att + bc * 64)[w >> 2];
        float4 xv = reinterpret_cast<const float4*>(x)[i];
        float4 ov;
        ov.x = xv.x * (ha * wa.x + ca);
        ov.y = xv.y * (ha * wa.y + ca);
        ov.z = xv.z * (ha * wa.z + ca);
        ov.w = xv.w * (ha * wa.w + ca);
        reinterpret_cast<float4*>(out)[i] = ov;
    }
}

// ---------------------------------------------------------------------------
extern "C" void kernel_launch(void* const* d_in, const int* in_sizes, int n_in,
                              void* d_out, int out_size, void* d_ws, size_t ws_size,
                              hipStream_t stream) {
    const float* x      = (const float*)d_in[0];
    const float* dw1    = (const float*)d_in[1];
    const float* db1    = (const float*)d_in[2];
    const float* dw2    = (const float*)d_in[3];
    const float* db2    = (const float*)d_in[4];
    const float* dw3    = (const float*)d_in[5];
    const float* db3    = (const float*)d_in[6];
    const float* dw4    = (const float*)d_in[7];
    const float* db4    = (const float*)d_in[8];
    const float* gnh_w  = (const float*)d_in[9];
    const float* gnh_b  = (const float*)d_in[10];
    const float* gnw_w  = (const float*)d_in[11];
    const float* gnw_b  = (const float*)d_in[12];
    const float* norm_w = (const float*)d_in[13];
    const float* norm_b = (const float*)d_in[14];
    const float* wq     = (const float*)d_in[15];
    const float* wk     = (const float*)d_in[16];
    const float* wv     = (const float*)d_in[17];
    float* out = (float*)d_out;

    float* ws   = (float*)d_ws;
    const size_t PLANE = (size_t)BB * CC * 64;   // 524288 floats
    float* xh   = ws;                 // (b,c,64) row means
    float* xw   = xh + PLANE;         // (b,c,64) col means
    float* yy   = xw + PLANE;         // (b,c,64) pooled
    float* hatt = yy + PLANE;         // (b,c,64)
    float* watt = hatt + PLANE;       // (b,c,64)
    float* catt = watt + PLANE;       // (b,c)

    k_reduce<<<BB * CC, 256, 0, stream>>>(x, xh, xw, yy);
    k_strip<<<BB * 8, 256, 0, stream>>>(xh, xw, dw1, db1, dw2, db2, dw3, db3,
                                        dw4, db4, gnh_w, gnh_b, gnw_w, gnw_b,
                                        hatt, watt);
    k_pool_att<<<BB, 256, 0, stream>>>(yy, norm_w, norm_b, wq, wk, wv, catt);
    k_final<<<2048, 256, 0, stream>>>(x, hatt, watt, catt, out);
}

// Round 5
// 300.943 us; speedup vs baseline: 1.0656x; 1.0656x over previous
//
#include <hip/hip_runtime.h>
#include <hip/hip_bf16.h>

#define BB 32
#define CC 256
#define GC 64
#define LL 64      // H == W == 64
#define HEADS 8
#define HD 32

typedef float f32x4 __attribute__((ext_vector_type(4)));

// ---------------------------------------------------------------------------
// K1: per (b,c) plane (64x64): row means (over w), col means (over h),
//     8x8 patch-pool means.  One block per plane, 256 threads.
// ---------------------------------------------------------------------------
__global__ __launch_bounds__(256) void k_reduce(const float* __restrict__ x,
                                                float* __restrict__ xh,
                                                float* __restrict__ xw,
                                                float* __restrict__ y) {
    __shared__ float sm[64 * 65];   // padded stride 65 -> conflict-free
    const int bc  = blockIdx.x;     // b*C + c
    const int tid = threadIdx.x;
    const float* xp = x + (size_t)bc * 4096;

    for (int i = tid; i < 1024; i += 256) {
        float4 v = reinterpret_cast<const float4*>(xp)[i];
        int h = (i * 4) >> 6, w = (i * 4) & 63;
        float* row = &sm[h * 65 + w];
        row[0] = v.x; row[1] = v.y; row[2] = v.z; row[3] = v.w;
    }
    __syncthreads();

    const int q = tid & 3, r = tid >> 2;   // r in 0..63

    // row sums (mean over w) -> xh[b,c,h]
    float s = 0.f;
#pragma unroll
    for (int j = 0; j < 16; ++j) s += sm[r * 65 + q * 16 + j];
    s += __shfl_down(s, 2, 4);
    s += __shfl_down(s, 1, 4);
    if (q == 0) xh[(size_t)bc * 64 + r] = s * (1.0f / 64.0f);

    // col sums (mean over h) -> xw[b,c,w]
    s = 0.f;
#pragma unroll
    for (int j = 0; j < 16; ++j) s += sm[(q * 16 + j) * 65 + r];
    s += __shfl_down(s, 2, 4);
    s += __shfl_down(s, 1, 4);
    if (q == 0) xw[(size_t)bc * 64 + r] = s * (1.0f / 64.0f);

    // 8x8 patch means -> y[b,c,ph*8+pw]
    if (tid < 64) {
        int ph = tid >> 3, pw = tid & 7;
        float ps = 0.f;
        for (int rr = 0; rr < 8; ++rr)
#pragma unroll
            for (int cci = 0; cci < 8; ++cci)
                ps += sm[(ph * 8 + rr) * 65 + pw * 8 + cci];
        y[(size_t)bc * 64 + tid] = ps * (1.0f / 64.0f);
    }
}

// ---------------------------------------------------------------------------
// K2: fused strip attention (blocks 0..255) + pooled channel self-attention
//     (blocks 256..287).  The two halves are independent; both consume K1
//     outputs only.
// ---------------------------------------------------------------------------
__global__ __launch_bounds__(256) void k_mid(
        const float* __restrict__ xh, const float* __restrict__ xw,
        const float* __restrict__ dw1, const float* __restrict__ db1,
        const float* __restrict__ dw2, const float* __restrict__ db2,
        const float* __restrict__ dw3, const float* __restrict__ db3,
        const float* __restrict__ dw4, const float* __restrict__ db4,
        const float* __restrict__ gnh_w, const float* __restrict__ gnh_b,
        const float* __restrict__ gnw_w, const float* __restrict__ gnw_b,
        float* __restrict__ h_att, float* __restrict__ w_att,
        const float* __restrict__ y,
        const float* __restrict__ norm_w, const float* __restrict__ norm_b,
        const float* __restrict__ wq, const float* __restrict__ wk,
        const float* __restrict__ wv, float* __restrict__ c_att) {
    __shared__ float sm[CC * 65];          // 66560 B (pool half uses all)
    __shared__ float aux[CC * 2 + 8];
    const int tid = threadIdx.x;

    if (blockIdx.x < 256) {
        // ------------------ strip attention ------------------
        float* red = aux;
        const int bx  = blockIdx.x;          // b*8 + dir*4 + g
        const int b   = bx >> 3;
        const int dir = (bx >> 2) & 1;
        const int g   = bx & 3;

        const float* src = (dir ? xw : xh) + ((size_t)b * CC + g * GC) * 64;
        float*       dst = (dir ? w_att : h_att) + ((size_t)b * CC + g * GC) * 64;
        const float* gw  = (dir ? gnw_w : gnh_w) + g * GC;
        const float* gb  = (dir ? gnw_b : gnh_b) + g * GC;

        const float* dwp; const float* dbp; int k;
        if      (g == 0) { dwp = dw1; dbp = db1; k = 3; }
        else if (g == 1) { dwp = dw2; dbp = db2; k = 5; }
        else if (g == 2) { dwp = dw3; dbp = db3; k = 7; }
        else             { dwp = dw4; dbp = db4; k = 9; }

        for (int i = tid; i < 1024; i += 256) {
            float4 v = reinterpret_cast<const float4*>(src)[i];
            int ch = (i * 4) >> 6, l = (i * 4) & 63;
            float* row = &sm[ch * 65 + l];
            row[0] = v.x; row[1] = v.y; row[2] = v.z; row[3] = v.w;
        }
        __syncthreads();

        const int ch = tid >> 2, q = tid & 3;
        const int khalf = k >> 1;
        float wreg[9];
        for (int j = 0; j < 9; ++j) wreg[j] = (j < k) ? dwp[ch * k + j] : 0.0f;
        const float bias = dbp[ch];

        float o[16];
        float lsum = 0.f, lsq = 0.f;
        for (int i = 0; i < 16; ++i) {
            int l = q * 16 + i;
            float acc = bias;
            for (int j = 0; j < k; ++j) {
                int p = l + j - khalf;
                if (p >= 0 && p < 64) acc += wreg[j] * sm[ch * 65 + p];
            }
            o[i] = acc;
            lsum += acc; lsq += acc * acc;
        }
        for (int off = 32; off; off >>= 1) {
            lsum += __shfl_down(lsum, off, 64);
            lsq  += __shfl_down(lsq,  off, 64);
        }
        const int wid = tid >> 6, lane = tid & 63;
        if (lane == 0) { red[wid] = lsum; red[4 + wid] = lsq; }
        __syncthreads();
        const float tsum = red[0] + red[1] + red[2] + red[3];
        const float tsq  = red[4] + red[5] + red[6] + red[7];
        const float m    = tsum * (1.0f / 4096.0f);
        const float var  = tsq * (1.0f / 4096.0f) - m * m;
        const float rstd = rsqrtf(var + 1e-5f);
        const float gamma = gw[ch], beta = gb[ch];

        float outv[16];
#pragma unroll
        for (int i = 0; i < 16; ++i) {
            float v = (o[i] - m) * rstd * gamma + beta;
            outv[i] = 1.0f / (1.0f + __expf(-v));
        }
        float* dp = dst + ch * 64 + q * 16;
#pragma unroll
        for (int i = 0; i < 16; i += 4) {
            reinterpret_cast<float4*>(dp + i)[0] =
                make_float4(outv[i], outv[i + 1], outv[i + 2], outv[i + 3]);
        }
    } else {
        // ------------------ pooled channel self-attention ------------------
        float* yn   = sm;                 // [CC][65]
        float* vbar = aux;                // [CC]
        float* kwv  = aux + CC;           // [CC]
        float* red  = aux + 2 * CC;       // [8]
        const int b = blockIdx.x - 256;
        const float* yp = y + (size_t)b * CC * 64;

        for (int i = tid; i < 4096; i += 256) {
            float4 v = reinterpret_cast<const float4*>(yp)[i];
            int ch = (i * 4) >> 6, n0 = (i * 4) & 63;
            float* row = &yn[ch * 65 + n0];
            row[0] = v.x; row[1] = v.y; row[2] = v.z; row[3] = v.w;
        }
        __syncthreads();

        const int ch = tid;              // one channel per thread
        float lsum = 0.f, lsq = 0.f;
        for (int n = 0; n < 64; ++n) {
            float v = yn[ch * 65 + n];
            lsum += v; lsq += v * v;
        }
        for (int off = 32; off; off >>= 1) {
            lsum += __shfl_down(lsum, off, 64);
            lsq  += __shfl_down(lsq,  off, 64);
        }
        const int wid = tid >> 6, lane = tid & 63;
        if (lane == 0) { red[wid] = lsum; red[4 + wid] = lsq; }
        __syncthreads();
        const float tsum = red[0] + red[1] + red[2] + red[3];
        const float tsq  = red[4] + red[5] + red[6] + red[7];
        const float m    = tsum * (1.0f / 16384.0f);
        const float var  = tsq * (1.0f / 16384.0f) - m * m;
        const float rstd = rsqrtf(var + 1e-5f);

        const float gamma = norm_w[ch], beta = norm_b[ch];
        float rs = 0.f;
        for (int n = 0; n < 64; ++n) {
            float v = (yn[ch * 65 + n] - m) * rstd * gamma + beta;
            yn[ch * 65 + n] = v;
            rs += v;
        }
        vbar[ch] = rs * (1.0f / 64.0f) * wv[ch];
        kwv[ch]  = wk[ch];
        __syncthreads();

        const int head = ch >> 5;
        const float qs = wq[ch] * 0.17677669529663687f;   // * hd^-0.5
        const float* myrow = &yn[ch * 65];
        float s[HD];
        for (int e = 0; e < HD; ++e) {
            const float* erow = &yn[(head * HD + e) * 65];
            float acc = 0.f;
#pragma unroll
            for (int n = 0; n < 64; ++n) acc += myrow[n] * erow[n];
            s[e] = acc * qs * kwv[head * HD + e];
        }
        float mx = s[0];
#pragma unroll
        for (int e = 1; e < HD; ++e) mx = fmaxf(mx, s[e]);
        float den = 0.f;
#pragma unroll
        for (int e = 0; e < HD; ++e) { s[e] = __expf(s[e] - mx); den += s[e]; }
        float o = 0.f;
#pragma unroll
        for (int e = 0; e < HD; ++e) o += s[e] * vbar[head * HD + e];
        o /= den;
        c_att[(size_t)b * CC + ch] = 1.0f / (1.0f + __expf(-o));
    }
}

// ---------------------------------------------------------------------------
// K3: out = x * (h_att[b,c,h] * w_att[b,c,w] + c_att[b,c])
//     Non-temporal stores: out is write-once, keep x/atts cache-resident.
// ---------------------------------------------------------------------------
__global__ __launch_bounds__(256) void k_final(
        const float* __restrict__ x, const float* __restrict__ h_att,
        const float* __restrict__ w_att, const float* __restrict__ c_att,
        float* __restrict__ out) {
    const size_t total4 = (size_t)BB * CC * LL * LL / 4;   // 8,388,608
    const size_t stride = (size_t)gridDim.x * blockDim.x;
    for (size_t i = (size_t)blockIdx.x * blockDim.x + threadIdx.x;
         i < total4; i += stride) {
        size_t lin = i * 4;
        int w = (int)(lin & 63);
        int h = (int)((lin >> 6) & 63);
        size_t bc = lin >> 12;          // b*C + c
        float ha = h_att[bc * 64 + h];
        float ca = c_att[bc];
        f32x4 wa = reinterpret_cast<const f32x4*>(w_att + bc * 64)[w >> 2];
        f32x4 xv = reinterpret_cast<const f32x4*>(x)[i];
        f32x4 ov;
        ov.x = xv.x * (ha * wa.x + ca);
        ov.y = xv.y * (ha * wa.y + ca);
        ov.z = xv.z * (ha * wa.z + ca);
        ov.w = xv.w * (ha * wa.w + ca);
        __builtin_nontemporal_store(ov, reinterpret_cast<f32x4*>(out) + i);
    }
}

// ---------------------------------------------------------------------------
extern "C" void kernel_launch(void* const* d_in, const int* in_sizes, int n_in,
                              void* d_out, int out_size, void* d_ws, size_t ws_size,
                              hipStream_t stream) {
    const float* x      = (const float*)d_in[0];
    const float* dw1    = (const float*)d_in[1];
    const float* db1    = (const float*)d_in[2];
    const float* dw2    = (const float*)d_in[3];
    const float* db2    = (const float*)d_in[4];
    const float* dw3    = (const float*)d_in[5];
    const float* db3    = (const float*)d_in[6];
    const float* dw4    = (const float*)d_in[7];
    const float* db4    = (const float*)d_in[8];
    const float* gnh_w  = (const float*)d_in[9];
    const float* gnh_b  = (const float*)d_in[10];
    const float* gnw_w  = (const float*)d_in[11];
    const float* gnw_b  = (const float*)d_in[12];
    const float* norm_w = (const float*)d_in[13];
    const float* norm_b = (const float*)d_in[14];
    const float* wq     = (const float*)d_in[15];
    const float* wk     = (const float*)d_in[16];
    const float* wv     = (const float*)d_in[17];
    float* out = (float*)d_out;

    float* ws   = (float*)d_ws;
    const size_t PLANE = (size_t)BB * CC * 64;   // 524288 floats
    float* xh   = ws;                 // (b,c,64) row means
    float* xw   = xh + PLANE;         // (b,c,64) col means
    float* yy   = xw + PLANE;         // (b,c,64) pooled
    float* hatt = yy + PLANE;         // (b,c,64)
    float* watt = hatt + PLANE;       // (b,c,64)
    float* catt = watt + PLANE;       // (b,c)

    k_reduce<<<BB * CC, 256, 0, stream>>>(x, xh, xw, yy);
    k_mid<<<BB * 8 + BB, 256, 0, stream>>>(xh, xw, dw1, db1, dw2, db2,
                                           dw3, db3, dw4, db4,
                                           gnh_w, gnh_b, gnw_w, gnw_b,
                                           hatt, watt,
                                           yy, norm_w, norm_b, wq, wk, wv, catt);
    k_final<<<2048, 256, 0, stream>>>(x, hatt, watt, catt, out);
}